// Round 1
// baseline (145.476 us; speedup 1.0000x reference)
//
#include <hip/hip_runtime.h>
#include <math.h>

#define BATCH 1024
#define IN_DIM 256
#define NG 512
#define OUT_DIM 256

// ---------------------------------------------------------------------------
// Kernel 1: per-gaussian precompute.  w = 1/s^2, A = w, B = -2*c*w,
// K[g] = sum_d c^2 * w.   512 blocks x 256 threads (one thread per dim).
// ---------------------------------------------------------------------------
__global__ __launch_bounds__(256) void prep_gauss(
    const float* __restrict__ centers, const float* __restrict__ stds,
    float* __restrict__ A, float* __restrict__ B, float* __restrict__ K) {
  int g = blockIdx.x;
  int d = threadIdx.x;
  float c = centers[g * IN_DIM + d];
  float s = stds[g * IN_DIM + d];
  float w = 1.0f / (s * s);
  A[g * IN_DIM + d] = w;
  B[g * IN_DIM + d] = -2.0f * c * w;
  float kt = c * c * w;
#pragma unroll
  for (int off = 32; off > 0; off >>= 1) kt += __shfl_down(kt, off, 64);
  __shared__ float part[4];
  int wavei = threadIdx.x >> 6;
  int lane = threadIdx.x & 63;
  if (lane == 0) part[wavei] = kt;
  __syncthreads();
  if (threadIdx.x == 0) K[g] = part[0] + part[1] + part[2] + part[3];
}

// ---------------------------------------------------------------------------
// Kernel 2: transpose x -> xT[d][b] and x2T[d][b] = x^2.
// grid (32, 8), block (32, 32); LDS tile with +1 pad.
// ---------------------------------------------------------------------------
__global__ void prep_x(const float* __restrict__ x, float* __restrict__ xT,
                       float* __restrict__ x2T) {
  __shared__ float t[32][33];
  int tx = threadIdx.x, ty = threadIdx.y;
  int d = blockIdx.y * 32 + tx;  // coalesced read along d
  int b = blockIdx.x * 32 + ty;
  t[ty][tx] = x[b * IN_DIM + d];
  __syncthreads();
  int dw = blockIdx.y * 32 + ty;
  int bw = blockIdx.x * 32 + tx;  // coalesced write along b
  float v = t[tx][ty];
  xT[dw * BATCH + bw] = v;
  x2T[dw * BATCH + bw] = v * v;
}

// ---------------------------------------------------------------------------
// Kernel 3: main gaussian kernel.
// 2048 waves: wave -> (batch-group of 64, chunk of 4 gaussians).
// lane = batch row.  A/B/K indices are wave-uniform -> scalar loads.
// 2 FMA per (b,g,d) element-op.
// ---------------------------------------------------------------------------
__global__ __launch_bounds__(256) void gauss_main(
    const float* __restrict__ xT, const float* __restrict__ x2T,
    const float* __restrict__ A, const float* __restrict__ B,
    const float* __restrict__ K, float* __restrict__ GT) {
  int wid = __builtin_amdgcn_readfirstlane((blockIdx.x * 256 + threadIdx.x) >> 6);
  int lane = threadIdx.x & 63;
  int bg = wid & 15;         // 16 batch groups
  int g0 = (wid >> 4) * 4;   // 128 gaussian chunks of 4
  int b = bg * 64 + lane;

  float acc[4] = {0.f, 0.f, 0.f, 0.f};
  for (int d0 = 0; d0 < IN_DIM; d0 += 8) {
    float xv[8], x2v[8];
#pragma unroll
    for (int j = 0; j < 8; ++j) {
      xv[j] = xT[(d0 + j) * BATCH + b];
      x2v[j] = x2T[(d0 + j) * BATCH + b];
    }
#pragma unroll
    for (int g = 0; g < 4; ++g) {
#pragma unroll
      for (int j = 0; j < 8; ++j) {
        float a = A[(g0 + g) * IN_DIM + d0 + j];   // wave-uniform -> s_load
        float bb = B[(g0 + g) * IN_DIM + d0 + j];  // wave-uniform -> s_load
        acc[g] = fmaf(x2v[j], a, fmaf(xv[j], bb, acc[g]));
      }
    }
  }
#pragma unroll
  for (int g = 0; g < 4; ++g) {
    float e = -0.5f * (acc[g] + K[g0 + g]);
    GT[(g0 + g) * BATCH + b] = __expf(e);  // coalesced store (lane = b)
  }
}

// ---------------------------------------------------------------------------
// Kernel 4: out[b,o] = sum_g GT[g][b] * W[g][o].
// 512 waves: wave -> (o-group of 64, batch chunk of 8).
// lane = o.  GT values are wave-uniform -> scalar dwordx8 loads.
// ---------------------------------------------------------------------------
__global__ __launch_bounds__(256) void gemm_out(
    const float* __restrict__ GT, const float* __restrict__ W,
    float* __restrict__ out) {
  int wid = __builtin_amdgcn_readfirstlane((blockIdx.x * 256 + threadIdx.x) >> 6);
  int lane = threadIdx.x & 63;
  int og = wid & 3;          // 4 o-groups of 64
  int b0 = (wid >> 2) * 8;   // 128 batch chunks of 8
  int o = og * 64 + lane;

  float acc[8] = {0.f, 0.f, 0.f, 0.f, 0.f, 0.f, 0.f, 0.f};
  for (int g = 0; g < NG; ++g) {
    float wv = W[g * OUT_DIM + o];  // coalesced (lane = o)
#pragma unroll
    for (int i = 0; i < 8; ++i) {
      float gv = GT[g * BATCH + b0 + i];  // wave-uniform -> s_load_dwordx8
      acc[i] = fmaf(gv, wv, acc[i]);
    }
  }
#pragma unroll
  for (int i = 0; i < 8; ++i)
    out[(b0 + i) * OUT_DIM + o] = acc[i];  // coalesced (lane = o)
}

// ---------------------------------------------------------------------------
extern "C" void kernel_launch(void* const* d_in, const int* in_sizes, int n_in,
                              void* d_out, int out_size, void* d_ws,
                              size_t ws_size, hipStream_t stream) {
  const float* x = (const float*)d_in[0];        // [1024, 256]
  const float* centers = (const float*)d_in[1];  // [512, 256]
  const float* stds = (const float*)d_in[2];     // [512, 256]
  const float* weights = (const float*)d_in[3];  // [512, 256]
  float* out = (float*)d_out;                    // [1024, 256]

  float* ws = (float*)d_ws;
  float* A = ws;                   // 131072
  float* B = ws + 131072;          // 131072
  float* K = ws + 262144;          // 512
  float* xT = ws + 262656;         // 262144
  float* x2T = ws + 524800;        // 262144
  float* GT = ws + 786944;         // 524288  (end: 1311232 floats ~ 5.25 MB)

  prep_gauss<<<NG, 256, 0, stream>>>(centers, stds, A, B, K);
  prep_x<<<dim3(32, 8), dim3(32, 32), 0, stream>>>(x, xT, x2T);
  gauss_main<<<512, 256, 0, stream>>>(xT, x2T, A, B, K, GT);
  gemm_out<<<128, 256, 0, stream>>>(GT, weights, out);
}

// Round 2
// 101.666 us; speedup vs baseline: 1.4309x; 1.4309x over previous
//
#include <hip/hip_runtime.h>
#include <math.h>

#define BATCH 1024
#define IN_DIM 256
#define NG 512
#define OUT_DIM 256

// ---------------------------------------------------------------------------
// Kernel 1 (merged prep), 896 blocks x 256 threads:
//   blocks [0,512):    per-gaussian A = 1/s^2, B = -2c/s^2, K[g] = sum c^2/s^2
//   blocks [512,768):  transpose x -> xT4: quad-of-d per lane, [d/4][b] float4
//   blocks [768,896):  transpose W -> W4:  quad-of-g per lane, [g/4][o] float4
// ---------------------------------------------------------------------------
__global__ __launch_bounds__(256) void prep_all(
    const float* __restrict__ x, const float* __restrict__ centers,
    const float* __restrict__ stds, const float* __restrict__ W,
    float* __restrict__ A, float* __restrict__ B, float* __restrict__ K,
    float4* __restrict__ xT4, float4* __restrict__ W4) {
  int bid = blockIdx.x;
  __shared__ float t32[32][33];
  if (bid < NG) {
    int g = bid, d = threadIdx.x;
    float c = centers[g * IN_DIM + d];
    float s = stds[g * IN_DIM + d];
    float w = 1.0f / (s * s);
    A[g * IN_DIM + d] = w;
    B[g * IN_DIM + d] = -2.0f * c * w;
    float kt = c * c * w;
#pragma unroll
    for (int off = 32; off > 0; off >>= 1) kt += __shfl_down(kt, off, 64);
    __shared__ float part[4];
    int lane = threadIdx.x & 63;
    if (lane == 0) part[threadIdx.x >> 6] = kt;
    __syncthreads();
    if (threadIdx.x == 0) K[g] = part[0] + part[1] + part[2] + part[3];
  } else if (bid < NG + 256) {
    // x transpose: 32 b-tiles x 8 d-tiles of 32x32
    int tb = bid - NG;
    int bb = (tb & 31) * 32, db = (tb >> 5) * 32;
    int tx = threadIdx.x & 31, iy = threadIdx.x >> 5;
#pragma unroll
    for (int r = 0; r < 4; ++r) {
      int i = iy + r * 8;
      t32[i][tx] = x[(bb + i) * IN_DIM + db + tx];  // coalesced along d
    }
    __syncthreads();
    int q = threadIdx.x >> 5;  // d-quad 0..7
    float4 v = make_float4(t32[tx][4 * q + 0], t32[tx][4 * q + 1],
                           t32[tx][4 * q + 2], t32[tx][4 * q + 3]);
    xT4[(db / 4 + q) * BATCH + bb + tx] = v;  // coalesced along b
  } else {
    // W transpose: 16 g-tiles x 8 o-tiles of 32x32
    int tb = bid - NG - 256;
    int ob = (tb & 7) * 32, gb = (tb >> 3) * 32;
    int tx = threadIdx.x & 31, iy = threadIdx.x >> 5;
#pragma unroll
    for (int r = 0; r < 4; ++r) {
      int i = iy + r * 8;
      t32[i][tx] = W[(gb + i) * OUT_DIM + ob + tx];  // coalesced along o
    }
    __syncthreads();
    int q = threadIdx.x >> 5;  // g-quad 0..7
    float4 v = make_float4(t32[4 * q + 0][tx], t32[4 * q + 1][tx],
                           t32[4 * q + 2][tx], t32[4 * q + 3][tx]);
    W4[(gb / 4 + q) * OUT_DIM + ob + tx] = v;  // coalesced along o
  }
}

// ---------------------------------------------------------------------------
// Kernel 2: exponent + exp.  512 blocks x 256 thr = 2048 waves (2/SIMD).
// Block: (batch-group of 64) x (16 gaussians); wave handles 4 gaussians.
// lane = b.  A/B/K wave-uniform -> scalar loads; x via float4 (4 d's/load).
// 8 d per iter: 2 dwordx4 vmem + 8 mul + 64 fma.
// ---------------------------------------------------------------------------
__global__ __launch_bounds__(256) void gauss_main(
    const float4* __restrict__ xT4, const float* __restrict__ A,
    const float* __restrict__ B, const float* __restrict__ K,
    float* __restrict__ GT) {
  int wid = __builtin_amdgcn_readfirstlane(threadIdx.x >> 6);
  int lane = threadIdx.x & 63;
  int bg = blockIdx.x & 15;
  int gc = blockIdx.x >> 4;  // 0..31
  int g0 = gc * 16 + wid * 4;
  int b = bg * 64 + lane;

  const float* Ap = A + g0 * IN_DIM;
  const float* Bp = B + g0 * IN_DIM;
  float acc[4] = {0.f, 0.f, 0.f, 0.f};
  for (int dq = 0; dq < IN_DIM / 4; dq += 2) {
    float4 xa = xT4[dq * BATCH + b];
    float4 xb = xT4[(dq + 1) * BATCH + b];
    float xv[8] = {xa.x, xa.y, xa.z, xa.w, xb.x, xb.y, xb.z, xb.w};
    float xs[8];
#pragma unroll
    for (int j = 0; j < 8; ++j) xs[j] = xv[j] * xv[j];
    int d0 = dq * 4;
#pragma unroll
    for (int g = 0; g < 4; ++g) {
#pragma unroll
      for (int j = 0; j < 8; ++j) {
        float av = Ap[g * IN_DIM + d0 + j];  // uniform -> s_load
        float bv = Bp[g * IN_DIM + d0 + j];  // uniform -> s_load
        acc[g] = fmaf(xs[j], av, fmaf(xv[j], bv, acc[g]));
      }
    }
  }
#pragma unroll
  for (int g = 0; g < 4; ++g) {
    float e = -0.5f * (acc[g] + K[g0 + g]);
    GT[(g0 + g) * BATCH + b] = __expf(e);  // coalesced (lane = b)
  }
}

// ---------------------------------------------------------------------------
// Kernel 3: split-K GEMM partials. part[kg][b][o] = sum_{g in kg-chunk} GT*W.
// 512 blocks x 256 thr: block = (bc-group of 32 b, og, kg); wave = 8 b rows.
// All 4 waves in a block share the same 32KB W4 slab (L1 reuse).
// 8 g per iter: 2 dwordx4 (W4) + 8 s_load_dwordx8 (GT) + 64 fma.
// ---------------------------------------------------------------------------
__global__ __launch_bounds__(256) void gemm_partial(
    const float* __restrict__ GT, const float4* __restrict__ W4,
    float* __restrict__ part) {
  int kg = blockIdx.x & 3;
  int og = (blockIdx.x >> 2) & 3;
  int bcg = blockIdx.x >> 4;  // 0..31
  int wid = __builtin_amdgcn_readfirstlane(threadIdx.x >> 6);
  int lane = threadIdx.x & 63;
  int b0 = bcg * 32 + wid * 8;
  int o = og * 64 + lane;
  int gbase = kg * 128;

  float acc[8] = {0.f, 0.f, 0.f, 0.f, 0.f, 0.f, 0.f, 0.f};
  for (int gq = 0; gq < 32; gq += 2) {  // 8 g per iter
    int g = gbase + gq * 4;
    float4 w0 = W4[(gbase / 4 + gq) * OUT_DIM + o];
    float4 w1 = W4[(gbase / 4 + gq + 1) * OUT_DIM + o];
    float wv[8] = {w0.x, w0.y, w0.z, w0.w, w1.x, w1.y, w1.z, w1.w};
#pragma unroll
    for (int k = 0; k < 8; ++k) {
#pragma unroll
      for (int i = 0; i < 8; ++i) {
        float gv = GT[(g + k) * BATCH + b0 + i];  // uniform -> s_load_dwordx8
        acc[i] = fmaf(gv, wv[k], acc[i]);
      }
    }
  }
  float* pout = part + kg * (BATCH * OUT_DIM);
#pragma unroll
  for (int i = 0; i < 8; ++i)
    pout[(b0 + i) * OUT_DIM + o] = acc[i];  // coalesced (lane = o)
}

// ---------------------------------------------------------------------------
// Kernel 4: sum the 4 split-K partials. 256 blocks x 256 thr, float4.
// ---------------------------------------------------------------------------
__global__ __launch_bounds__(256) void reduce4(const float4* __restrict__ p,
                                               float4* __restrict__ out) {
  const int S = BATCH * OUT_DIM / 4;  // 65536 float4s
  int i = blockIdx.x * 256 + threadIdx.x;
  float4 a = p[i], b = p[i + S], c = p[i + 2 * S], d = p[i + 3 * S];
  float4 r;
  r.x = a.x + b.x + c.x + d.x;
  r.y = a.y + b.y + c.y + d.y;
  r.z = a.z + b.z + c.z + d.z;
  r.w = a.w + b.w + c.w + d.w;
  out[i] = r;
}

// ---------------------------------------------------------------------------
extern "C" void kernel_launch(void* const* d_in, const int* in_sizes, int n_in,
                              void* d_out, int out_size, void* d_ws,
                              size_t ws_size, hipStream_t stream) {
  const float* x = (const float*)d_in[0];        // [1024, 256]
  const float* centers = (const float*)d_in[1];  // [512, 256]
  const float* stds = (const float*)d_in[2];     // [512, 256]
  const float* weights = (const float*)d_in[3];  // [512, 256]
  float* out = (float*)d_out;                    // [1024, 256]

  float* ws = (float*)d_ws;
  float* A = ws;                       // 131072
  float* B = ws + 131072;              // 131072
  float* K = ws + 262144;              // 512 (+pad to 262656, 16B-aligned)
  float4* xT4 = (float4*)(ws + 262656);   // 262144 floats
  float4* W4 = (float4*)(ws + 524800);    // 131072 floats
  float* GT = ws + 655872;             // 524288
  float* part = ws + 1180160;          // 1048576 (end 2228736 fl ~ 8.5 MB)

  prep_all<<<896, 256, 0, stream>>>(x, centers, stds, weights, A, B, K, xT4,
                                    W4);
  gauss_main<<<512, 256, 0, stream>>>(xT4, A, B, K, GT);
  gemm_partial<<<512, 256, 0, stream>>>(GT, (const float4*)W4, part);
  reduce4<<<256, 256, 0, stream>>>((const float4*)part, (float4*)out);
}

// Round 3
// 95.585 us; speedup vs baseline: 1.5219x; 1.0636x over previous
//
#include <hip/hip_runtime.h>
#include <math.h>

#define BATCH 1024
#define IN_DIM 256
#define NG 512
#define OUT_DIM 256

// ---------------------------------------------------------------------------
// Kernel 1 (merged prep), 896 blocks x 256 threads:
//   blocks [0,512):    per-gaussian A = 1/s^2, B = -2c/s^2, K[g] = sum c^2/s^2
//   blocks [512,768):  transpose x -> xT4: quad-of-d per lane, [d/4][b] float4
//   blocks [768,896):  transpose W -> W4:  quad-of-g per lane, [g/4][o] float4
// ---------------------------------------------------------------------------
__global__ __launch_bounds__(256) void prep_all(
    const float* __restrict__ x, const float* __restrict__ centers,
    const float* __restrict__ stds, const float* __restrict__ W,
    float* __restrict__ A, float* __restrict__ B, float* __restrict__ K,
    float4* __restrict__ xT4, float4* __restrict__ W4) {
  int bid = blockIdx.x;
  __shared__ float t32[32][33];
  if (bid < NG) {
    int g = bid, d = threadIdx.x;
    float c = centers[g * IN_DIM + d];
    float s = stds[g * IN_DIM + d];
    float w = 1.0f / (s * s);
    A[g * IN_DIM + d] = w;
    B[g * IN_DIM + d] = -2.0f * c * w;
    float kt = c * c * w;
#pragma unroll
    for (int off = 32; off > 0; off >>= 1) kt += __shfl_down(kt, off, 64);
    __shared__ float part[4];
    int lane = threadIdx.x & 63;
    if (lane == 0) part[threadIdx.x >> 6] = kt;
    __syncthreads();
    if (threadIdx.x == 0) K[g] = part[0] + part[1] + part[2] + part[3];
  } else if (bid < NG + 256) {
    // x transpose: 32 b-tiles x 8 d-tiles of 32x32
    int tb = bid - NG;
    int bb = (tb & 31) * 32, db = (tb >> 5) * 32;
    int tx = threadIdx.x & 31, iy = threadIdx.x >> 5;
#pragma unroll
    for (int r = 0; r < 4; ++r) {
      int i = iy + r * 8;
      t32[i][tx] = x[(bb + i) * IN_DIM + db + tx];  // coalesced along d
    }
    __syncthreads();
    int q = threadIdx.x >> 5;  // d-quad 0..7
    float4 v = make_float4(t32[tx][4 * q + 0], t32[tx][4 * q + 1],
                           t32[tx][4 * q + 2], t32[tx][4 * q + 3]);
    xT4[(db / 4 + q) * BATCH + bb + tx] = v;  // coalesced along b
  } else {
    // W transpose: 16 g-tiles x 8 o-tiles of 32x32
    int tb = bid - NG - 256;
    int ob = (tb & 7) * 32, gb = (tb >> 3) * 32;
    int tx = threadIdx.x & 31, iy = threadIdx.x >> 5;
#pragma unroll
    for (int r = 0; r < 4; ++r) {
      int i = iy + r * 8;
      t32[i][tx] = W[(gb + i) * OUT_DIM + ob + tx];  // coalesced along o
    }
    __syncthreads();
    int q = threadIdx.x >> 5;  // g-quad 0..7
    float4 v = make_float4(t32[4 * q + 0][tx], t32[4 * q + 1][tx],
                           t32[4 * q + 2][tx], t32[4 * q + 3][tx]);
    W4[(gb / 4 + q) * OUT_DIM + ob + tx] = v;  // coalesced along o
  }
}

// ---------------------------------------------------------------------------
// Kernel 2: partial exponent sums, split 4-ways over IN_DIM.
// 2048 blocks x 256 thr = 8192 waves = 8/SIMD (100% occupancy at <=64 VGPR).
// Block: (ds: d-quarter of 64) x (bg: 64 b) x (gc: 16 g); wave = 4 g.
// All 4 waves share the block's 16 KB x-tile via L1.
// ---------------------------------------------------------------------------
__global__ __launch_bounds__(256, 8) void gauss_partial(
    const float4* __restrict__ xT4, const float* __restrict__ A,
    const float* __restrict__ B, float* __restrict__ Ep) {
  int ds = blockIdx.x & 3;
  int bg = (blockIdx.x >> 2) & 15;
  int gc = blockIdx.x >> 6;  // 0..31
  int wid = __builtin_amdgcn_readfirstlane(threadIdx.x >> 6);
  int lane = threadIdx.x & 63;
  int g0 = gc * 16 + wid * 4;
  int b = bg * 64 + lane;
  int q0 = ds * 16;  // starting d-quad

  const float* Ap = A + g0 * IN_DIM;
  const float* Bp = B + g0 * IN_DIM;
  float acc[4] = {0.f, 0.f, 0.f, 0.f};
  for (int dq = 0; dq < 16; dq += 2) {
    float4 xa = xT4[(q0 + dq) * BATCH + b];
    float4 xb = xT4[(q0 + dq + 1) * BATCH + b];
    float xv[8] = {xa.x, xa.y, xa.z, xa.w, xb.x, xb.y, xb.z, xb.w};
    float xs[8];
#pragma unroll
    for (int j = 0; j < 8; ++j) xs[j] = xv[j] * xv[j];
    int d0 = ds * 64 + dq * 4;
#pragma unroll
    for (int g = 0; g < 4; ++g) {
#pragma unroll
      for (int j = 0; j < 8; ++j) {
        float av = Ap[g * IN_DIM + d0 + j];  // uniform -> s_load
        float bv = Bp[g * IN_DIM + d0 + j];  // uniform -> s_load
        acc[g] = fmaf(xs[j], av, fmaf(xv[j], bv, acc[g]));
      }
    }
  }
#pragma unroll
  for (int g = 0; g < 4; ++g)
    Ep[ds * (NG * BATCH) + (g0 + g) * BATCH + b] = acc[g];  // coalesced
}

// ---------------------------------------------------------------------------
// Kernel 3: combine 4 exponent partials + K, apply exp.
// 2048 blocks x 256 thr; thread -> (g, b).
// ---------------------------------------------------------------------------
__global__ __launch_bounds__(256, 8) void combine_exp(
    const float* __restrict__ Ep, const float* __restrict__ K,
    float* __restrict__ GT) {
  int g = blockIdx.x >> 2;
  int b = (blockIdx.x & 3) * 256 + threadIdx.x;
  int idx = g * BATCH + b;
  const int S = NG * BATCH;
  float e = Ep[idx] + Ep[idx + S] + Ep[idx + 2 * S] + Ep[idx + 3 * S] + K[g];
  GT[idx] = __expf(-0.5f * e);
}

// ---------------------------------------------------------------------------
// Kernel 4: split-K GEMM partials (K split 8 ways of 64 g).
// 1024 blocks x 256 thr = 4096 waves = 4/SIMD.
// Block: (kg of 8) x (og of 4) x (bc of 32); wave = 8 b rows, acc[8] ILP.
// All 4 waves share the block's 16 KB W4 slab via L1.
// ---------------------------------------------------------------------------
__global__ __launch_bounds__(256, 4) void gemm_partial(
    const float* __restrict__ GT, const float4* __restrict__ W4,
    float* __restrict__ part) {
  int kg = blockIdx.x & 7;
  int og = (blockIdx.x >> 3) & 3;
  int bc = blockIdx.x >> 5;  // 0..31
  int wid = __builtin_amdgcn_readfirstlane(threadIdx.x >> 6);
  int lane = threadIdx.x & 63;
  int b0 = bc * 32 + wid * 8;
  int o = og * 64 + lane;
  int gbase = kg * 64;

  float acc[8] = {0.f, 0.f, 0.f, 0.f, 0.f, 0.f, 0.f, 0.f};
  for (int gq = 0; gq < 16; ++gq) {  // 4 g per iter
    int g = gbase + gq * 4;
    float4 w = W4[(gbase / 4 + gq) * OUT_DIM + o];
    float wv[4] = {w.x, w.y, w.z, w.w};
#pragma unroll
    for (int k = 0; k < 4; ++k) {
#pragma unroll
      for (int i = 0; i < 8; ++i) {
        float gv = GT[(g + k) * BATCH + b0 + i];  // uniform -> s_load_dwordx8
        acc[i] = fmaf(gv, wv[k], acc[i]);
      }
    }
  }
  float* pout = part + kg * (BATCH * OUT_DIM);
#pragma unroll
  for (int i = 0; i < 8; ++i)
    pout[(b0 + i) * OUT_DIM + o] = acc[i];  // coalesced (lane = o)
}

// ---------------------------------------------------------------------------
// Kernel 5: sum the 8 split-K partials. 256 blocks x 256 thr, float4.
// ---------------------------------------------------------------------------
__global__ __launch_bounds__(256, 8) void reduce8(const float4* __restrict__ p,
                                                  float4* __restrict__ out) {
  const int S = BATCH * OUT_DIM / 4;  // 65536 float4s
  int i = blockIdx.x * 256 + threadIdx.x;
  float s0 = 0.f, s1 = 0.f, s2 = 0.f, s3 = 0.f;
#pragma unroll
  for (int k = 0; k < 8; ++k) {
    float4 v = p[i + k * S];
    s0 += v.x;
    s1 += v.y;
    s2 += v.z;
    s3 += v.w;
  }
  out[i] = make_float4(s0, s1, s2, s3);
}

// ---------------------------------------------------------------------------
extern "C" void kernel_launch(void* const* d_in, const int* in_sizes, int n_in,
                              void* d_out, int out_size, void* d_ws,
                              size_t ws_size, hipStream_t stream) {
  const float* x = (const float*)d_in[0];        // [1024, 256]
  const float* centers = (const float*)d_in[1];  // [512, 256]
  const float* stds = (const float*)d_in[2];     // [512, 256]
  const float* weights = (const float*)d_in[3];  // [512, 256]
  float* out = (float*)d_out;                    // [1024, 256]

  float* ws = (float*)d_ws;
  float* A = ws;                        // 131072
  float* B = ws + 131072;               // 131072
  float* K = ws + 262144;               // 512 (pad to 262656)
  float4* xT4 = (float4*)(ws + 262656); // 262144 floats
  float4* W4 = (float4*)(ws + 524800);  // 131072 floats
  float* GT = ws + 655872;              // 524288
  float* Ep = ws + 1180160;             // 4 x 524288 = 2097152
  float* part = ws + 3277312;           // 8 x 262144 = 2097152 (end ~21.5 MB)

  prep_all<<<896, 256, 0, stream>>>(x, centers, stds, weights, A, B, K, xT4,
                                    W4);
  gauss_partial<<<2048, 256, 0, stream>>>(xT4, A, B, Ep);
  combine_exp<<<2048, 256, 0, stream>>>(Ep, K, GT);
  gemm_partial<<<1024, 256, 0, stream>>>(GT, (const float4*)W4, part);
  reduce8<<<256, 256, 0, stream>>>((const float4*)part, (float4*)out);
}